// Round 17
// baseline (45.236 us; speedup 1.0000x reference)
//
#include <hip/hip_runtime.h>

#define NB 16
#define NC 256
#define NH 56
#define NW 56
#define NHW (NH * NW)          // 3136
#define NK 256
#define CAP 1024

// pass1 geometry: 8-row band x quarter channels per block -> 448 blocks.
// HALO-FREE: stage exactly the 8 compute rows; vprod edge rows (y0-1, y0+8)
// come from direct global loads (L2/L3 hits, bit-identical values).
#define BR 8                   // compute rows per band
#define RS 8                   // staged rows == compute rows (no halo)
#define CS 8                   // channels per staged chunk
#define CQ 64                  // channels per block (quarter)
#define NCHUNK (CQ / CS)       // 8 chunks per block
#define CHUNK16 (CS * RS * NW / 4)        // 896 16B-chunks per stage
#define NBAND (NH / BR)                   // 7
#define P1_BLOCKS (NB * NBAND * 4)        // 448 (56 per XCD)
#define NQ (BR * (NW / 4))                // 112 quads per band
#define MAPS (NB * NHW)                   // elements per map

// ---- sortable-float helpers -------------------------------------------------
__device__ inline unsigned int flip_f32(float f) {
    unsigned int u = __float_as_uint(f);
    return (u & 0x80000000u) ? ~u : (u | 0x80000000u);
}
__device__ inline float unflip_f32(unsigned int u) {
    u = (u & 0x80000000u) ? (u ^ 0x80000000u) : ~u;
    return __uint_as_float(u);
}

// ---- kernel 1: partial norm2 / hprod / vprod maps (halo-free staging) -------
__global__ void __launch_bounds__(256)
pass1_kernel(const float* __restrict__ f, float* __restrict__ maps) {
    __shared__ __align__(16) float buf[2][CS * RS * NW];   // 2 x 14336 B
    __shared__ float redbuf[NQ][2][12];                    // 10752 B
    // total 39.4 KB -> 4 blocks/CU (R13 was 46.6 KB -> 3)

    int bid = blockIdx.x;
    int sb = (bid & 7) * (P1_BLOCKS / 8) + (bid >> 3);   // XCD-chunked
    int b = sb / 28;
    int rem0 = sb - b * 28;
    int band = rem0 >> 2;          // 0..6
    int chq = rem0 & 3;            // channel quarter
    int y0 = band * BR;
    int tid = threadIdx.x;
    const float* fb = f + (size_t)b * NC * NHW + (size_t)chq * CQ * NHW;

    auto stage = [&](int ci, float* dst) {
        int c0 = ci * CS;
#pragma unroll
        for (int i = 0; i < 4; ++i) {
            int k = tid + 256 * i;
            if (k < CHUNK16) {
                int ch = k / (RS * 14);            // 112 16B-chunks per channel
                int rem = k - ch * (RS * 14);
                int rl = rem / 14;                 // staged row 0..7 (= y0+rl)
                int xk = rem - rl * 14;            // 16B chunk within row
                const float* src = fb + (size_t)(c0 + ch) * NHW + (y0 + rl) * NW + xk * 4;
                __builtin_amdgcn_global_load_lds(
                    (const __attribute__((address_space(1))) void*)src,
                    (__attribute__((address_space(3))) void*)(dst + k * 4),
                    16, 0, 0);
            }
        }
    };

    // compute geometry: tid<224 -> quad (8 rows x 14 quads) x chgroup(2)
    int chg = tid / NQ;                 // 0..1, each handles 4 ch per chunk
    int quad = tid - chg * NQ;          // 0..111
    int r = quad / 14, qx = quad - r * 14, x0 = qx * 4;
    int xl = x0 ? x0 - 1 : 0;
    int xr = (x0 + 4 < NW) ? x0 + 4 : NW - 1;
    const bool need_up_g = (r == BR - 1) && (y0 + BR < NH);   // global row y0+8
    const bool need_dn_g = (r == 0) && (y0 > 0);              // global row y0-1

    float n0 = 0.f, n1 = 0.f, n2 = 0.f, n3 = 0.f;
    float h0 = 0.f, h1 = 0.f, h2 = 0.f, h3 = 0.f;
    float w0 = 0.f, w1 = 0.f, w2 = 0.f, w3 = 0.f;

    stage(0, buf[0]);
    __syncthreads();                            // drains staging
    for (int ci = 0; ci < NCHUNK; ++ci) {
        if (ci + 1 < NCHUNK) stage(ci + 1, buf[(ci + 1) & 1]);
        if (tid < 2 * NQ) {
            const float* sbf = buf[ci & 1];
#pragma unroll
            for (int c = 0; c < 4; ++c) {
                const float* Bm = sbf + (chg * 4 + c) * (RS * NW) + r * NW;
                float4 v = *(const float4*)(Bm + x0);
                float  l = Bm[xl];
                float  rr = Bm[xr];
                // u = row clamp(y+1), d = row clamp(y-1); edge rows direct
                // from global (identical values -> bit-exact maps)
                float4 u, d;
                if (r < BR - 1) u = *(const float4*)(Bm + NW + x0);
                else if (need_up_g) {
                    const float* g = fb + (size_t)(ci * CS + chg * 4 + c) * NHW;
                    u = *(const float4*)(g + (y0 + BR) * NW + x0);
                } else u = v;                      // y=55: clamp(y+1)=y
                if (r > 0) d = *(const float4*)(Bm - NW + x0);
                else if (need_dn_g) {
                    const float* g = fb + (size_t)(ci * CS + chg * 4 + c) * NHW;
                    d = *(const float4*)(g + (y0 - 1) * NW + x0);
                } else d = v;                      // y=0: clamp(y-1)=y
                n0 += v.x * v.x; n1 += v.y * v.y; n2 += v.z * v.z; n3 += v.w * v.w;
                h0 += l * v.y;   h1 += v.x * v.z; h2 += v.y * v.w; h3 += v.z * rr;
                w0 += u.x * d.x; w1 += u.y * d.y; w2 += u.z * d.z; w3 += u.w * d.w;
            }
        }
        __syncthreads();   // compute done + next stage landed
    }

    if (tid < 2 * NQ) {
        float* rb = redbuf[quad][chg];
        rb[0] = n0; rb[1] = n1; rb[2]  = n2; rb[3]  = n3;
        rb[4] = h0; rb[5] = h1; rb[6]  = h2; rb[7]  = h3;
        rb[8] = w0; rb[9] = w1; rb[10] = w2; rb[11] = w3;
    }
    __syncthreads();

    // maps layout: [chq][class n/h/v][B*HW]
    float* mbase = maps + (size_t)chq * 3 * MAPS;
    for (int oi = tid; oi < NQ * 12; oi += 256) {
        int q = oi / 12, comp = oi - q * 12;
        float acc = redbuf[q][0][comp] + redbuf[q][1][comp];
        int r2 = q / 14, qx2 = q - r2 * 14;
        int j = comp & 3;
        float* m = mbase + (size_t)(comp >> 2) * MAPS;   // 0:n 1:h 2:v
        m[((size_t)b * NH + y0 + r2) * NW + qx2 * 4 + j] = acc;
    }
}

// ---- kernel 2: sim-finish (R13-exact, wide) ---------------------------------
__global__ void __launch_bounds__(256)
sim_kernel(const float* __restrict__ maps, unsigned int* __restrict__ sv) {
    int pix = blockIdx.x * 256 + threadIdx.x;
    if (pix >= NB * NHW) return;
    int b = pix / NHW, i = pix - b * NHW;

    int y = i / NW, x = i - y * NW;
    int xl = (x > 0) ? x - 1 : 0;
    int xr = (x < NW - 1) ? x + 1 : NW - 1;
    int yu = (y < NH - 1) ? y + 1 : NH - 1;
    int yd = (y > 0) ? y - 1 : 0;
    int il = y * NW + xl, ir = y * NW + xr;
    int iu = yu * NW + x, id = yd * NW + x;

    float nl = 0.f, nr = 0.f, nu = 0.f, nd = 0.f, h = 0.f, v = 0.f;
#pragma unroll
    for (int q = 0; q < 4; ++q) {
        const float* nq = maps + (size_t)(q * 3 + 0) * MAPS + (size_t)b * NHW;
        const float* hq = maps + (size_t)(q * 3 + 1) * MAPS + (size_t)b * NHW;
        const float* vq = maps + (size_t)(q * 3 + 2) * MAPS + (size_t)b * NHW;
        nl += nq[il]; nr += nq[ir]; nu += nq[iu]; nd += nq[id];
        h  += hq[i];  v  += vq[i];
    }
    float s = 0.5f * (h / (sqrtf(nl) * sqrtf(nr)) + v / (sqrtf(nu) * sqrtf(nd)));
    sv[pix] = flip_f32(s);
}

// ---- kernel 3: per-batch top-K (R13-exact) ----------------------------------
__global__ void __launch_bounds__(1024)
topk_kernel(const unsigned int* __restrict__ sv, int* __restrict__ idx_out,
            float* __restrict__ vals_out, float* __restrict__ y_out,
            float* __restrict__ x_out) {
    __shared__ unsigned int svals[NHW];
    __shared__ unsigned int hist[4096];
    __shared__ unsigned int wtot[16];
    __shared__ unsigned long long cand[CAP];
    __shared__ unsigned int sh_prefix, sh_mask;
    __shared__ int sh_above, sh_setS, sh_done, sh_cnt;

    const int b = blockIdx.x;
    const int tid = threadIdx.x;
    const int lane = tid & 63;
    const int wv = tid >> 6;
    const unsigned int* svb = sv + (size_t)b * NHW;

    for (int i = tid; i < NHW; i += 1024) svals[i] = svb[i];
    if (tid == 0) { sh_prefix = 0u; sh_mask = 0u; sh_above = 0; sh_done = 0; }

    const int shifts[3] = {20, 8, 0};
    const unsigned int wmasks[3] = {0xFFFu, 0xFFFu, 0xFFu};
    for (int st = 0; st < 3; ++st) {
        __syncthreads();
        int kneed = NK - sh_above;          // read post-barrier, pre-update
        if (sh_done) break;
        for (int i = tid; i < 4096; i += 1024) hist[i] = 0u;
        __syncthreads();
        unsigned int pfx = sh_prefix, msk = sh_mask;
        int shift = shifts[st];
        unsigned int wmask = wmasks[st];
        for (int i = tid; i < NHW; i += 1024) {
            unsigned int v = svals[i];
            if ((v & msk) == pfx) atomicAdd(&hist[(v >> shift) & wmask], 1u);
        }
        __syncthreads();
        unsigned int b0 = hist[4 * tid], b1 = hist[4 * tid + 1];
        unsigned int b2 = hist[4 * tid + 2], b3 = hist[4 * tid + 3];
        unsigned int lsum = b0 + b1 + b2 + b3;
        unsigned int s = lsum;
#pragma unroll
        for (int d = 1; d < 64; d <<= 1) {
            unsigned int t2 = __shfl_down(s, d);
            s += (lane + d < 64) ? t2 : 0u;
        }
        if (lane == 0) wtot[wv] = s;        // wave total
        __syncthreads();
        unsigned int wabove = 0;
        for (int w = wv + 1; w < 16; ++w) wabove += wtot[w];
        unsigned int thr_above = wabove + (s - lsum);   // strictly above my bins
        unsigned int suf3 = thr_above + b3;
        unsigned int suf2 = suf3 + b2;
        unsigned int suf1 = suf2 + b1;
        unsigned int suf0 = suf1 + b0;
        if (suf0 >= (unsigned int)kneed && thr_above < (unsigned int)kneed) {
            int c; unsigned int above, hc;
            if (suf3 >= (unsigned int)kneed)      { c = 4 * tid + 3; above = thr_above; hc = b3; }
            else if (suf2 >= (unsigned int)kneed) { c = 4 * tid + 2; above = suf3;      hc = b2; }
            else if (suf1 >= (unsigned int)kneed) { c = 4 * tid + 1; above = suf2;      hc = b1; }
            else                                  { c = 4 * tid + 0; above = suf1;      hc = b0; }
            sh_above += (int)above;
            sh_setS = (int)hc;
            sh_prefix = pfx | ((unsigned int)c << shift);
            sh_mask = msk | (wmask << shift);
            if (sh_above + sh_setS <= CAP || st == 2) sh_done = 1;
        }
    }
    __syncthreads();

    if (tid == 0) sh_cnt = 0;
    __syncthreads();
    unsigned int T = sh_prefix;
    for (int i = tid; i < NHW; i += 1024) {
        unsigned int v = svals[i];
        bool keep = (v >= T);
        unsigned long long m = __ballot(keep);
        int basep = 0;
        if (lane == 0) basep = atomicAdd(&sh_cnt, __popcll(m));
        basep = __shfl(basep, 0);
        if (keep) {
            int pos = basep + __popcll(m & ((1ull << lane) - 1ull));
            if (pos < CAP)
                cand[pos] = ((unsigned long long)v << 32) |
                            (unsigned long long)(0xFFFFFFFFu - (unsigned int)i);
        }
    }
    __syncthreads();
    int nc = sh_cnt; if (nc > CAP) nc = CAP;

    if (tid < nc) {
        unsigned long long my = cand[tid];
        int rank = 0;
        for (int i = 0; i < nc; ++i) rank += (cand[i] > my);
        if (rank < NK) {
            unsigned int lo = (unsigned int)(my & 0xFFFFFFFFull);
            int idx = (int)(0xFFFFFFFFu - lo);
            float val = unflip_f32((unsigned int)(my >> 32));
            int o = b * NK + rank;
            idx_out[o] = idx;
            vals_out[o] = val;
            y_out[o] = (float)(idx / NW);
            x_out[o] = (float)(idx % NW);
        }
    }
}

// ---- kernel 4: gather point features [B,K,C] (R13-exact scattered) ----------
#define GCT 8
__global__ void __launch_bounds__(256)
gather_kernel(const float* __restrict__ f, const int* __restrict__ idx,
              float* __restrict__ out) {
    int bid = blockIdx.x;              // 512 = 16 b x 32 ctiles
    int b = bid >> 5;
    int c0 = (bid & 31) * GCT;
    int t = threadIdx.x;               // point rank k
    int p = idx[b * NK + t];
    const float* fb = f + (size_t)b * NC * NHW + (size_t)c0 * NHW;

    float v[GCT];
#pragma unroll
    for (int ci = 0; ci < GCT; ++ci) v[ci] = fb[(size_t)ci * NHW + p];

    float4 a = make_float4(v[0], v[1], v[2], v[3]);
    float4 b4 = make_float4(v[4], v[5], v[6], v[7]);
    float* op = out + ((size_t)b * NK + t) * NC + c0;
    *(float4*)op = a;
    *(float4*)(op + 4) = b4;
}

extern "C" void kernel_launch(void* const* d_in, const int* in_sizes, int n_in,
                              void* d_out, int out_size, void* d_ws, size_t ws_size,
                              hipStream_t stream) {
    const float* f = (const float*)d_in[0];

    // output layout: point_feat [B,K,C] | vals [B,K] | ycoord [B,K] | xcoord [B,K]
    float* out_feat = (float*)d_out;
    float* out_vals = out_feat + (size_t)NB * NK * NC;
    float* out_y    = out_vals + (size_t)NB * NK;
    float* out_x    = out_y    + (size_t)NB * NK;

    // workspace: 12 partial maps (n,h,v x 4 quarters) | svals map | idx
    float* maps = (float*)d_ws;
    unsigned int* sv = (unsigned int*)(maps + 12 * (size_t)MAPS);
    int* idx = (int*)(sv + MAPS);

    pass1_kernel<<<P1_BLOCKS, 256, 0, stream>>>(f, maps);
    sim_kernel<<<(NB * NHW + 255) / 256, 256, 0, stream>>>(maps, sv);
    topk_kernel<<<NB, 1024, 0, stream>>>(sv, idx, out_vals, out_y, out_x);
    gather_kernel<<<NB * (NC / GCT), 256, 0, stream>>>(f, idx, out_feat);
}

// Round 18
// 38.449 us; speedup vs baseline: 1.1765x; 1.1765x over previous
//
#include <hip/hip_runtime.h>

#define NB 16
#define NC 256
#define NH 56
#define NW 56
#define NHW (NH * NW)          // 3136
#define NK 256
#define CAP 1024

// pass1 geometry (R13-exact): 8-row band x quarter channels -> 448 blocks
#define BR 8                   // compute rows per band
#define RS 10                  // staged rows (8 compute + 2 halo)
#define CS 8                   // channels per staged chunk
#define CQ 64                  // channels per block (quarter)
#define NCHUNK (CQ / CS)       // 8 chunks per block
#define CHUNK16 (CS * RS * NW / 4)        // 1120 16B-chunks per stage
#define NBAND (NH / BR)                   // 7
#define P1_BLOCKS (NB * NBAND * 4)        // 448 (56 per XCD)
#define NQ (BR * (NW / 4))                // 112 quads per band
#define MAPS (NB * NHW)                   // elements per map

// sim/hist geometry: 14 slices x 224 px per batch
#define SPB 14                 // slices per batch
#define SPX 224                // pixels per slice
#define NBIN 4096

// ---- sortable-float helpers -------------------------------------------------
__device__ inline unsigned int flip_f32(float f) {
    unsigned int u = __float_as_uint(f);
    return (u & 0x80000000u) ? ~u : (u | 0x80000000u);
}
__device__ inline float unflip_f32(unsigned int u) {
    u = (u & 0x80000000u) ? (u ^ 0x80000000u) : ~u;
    return __uint_as_float(u);
}

// ---- kernel 1: partial norm2 / hprod / vprod maps (R13-exact) ---------------
__global__ void __launch_bounds__(256)
pass1_kernel(const float* __restrict__ f, float* __restrict__ maps) {
    __shared__ __align__(16) float buf[2][CS * RS * NW];   // 2 x 17920 B
    __shared__ float redbuf[NQ][2][12];                    // 10752 B

    int bid = blockIdx.x;
    int sb = (bid & 7) * (P1_BLOCKS / 8) + (bid >> 3);   // XCD-chunked
    int b = sb / 28;
    int rem0 = sb - b * 28;
    int band = rem0 >> 2;          // 0..6
    int chq = rem0 & 3;            // channel quarter
    int y0 = band * BR;
    int tid = threadIdx.x;
    const float* fb = f + (size_t)b * NC * NHW + (size_t)chq * CQ * NHW;

    auto stage = [&](int ci, float* dst) {
        int c0 = ci * CS;
#pragma unroll
        for (int i = 0; i < 5; ++i) {
            int k = tid + 256 * i;
            if (k < CHUNK16) {
                int ch = k / (RS * 14);            // 140 16B-chunks per channel
                int rem = k - ch * (RS * 14);
                int rl = rem / 14;                 // staged row 0..9
                int xk = rem - rl * 14;            // 16B chunk within row
                int rg = y0 - 1 + rl;
                rg = rg < 0 ? 0 : (rg > NH - 1 ? NH - 1 : rg);
                const float* src = fb + (size_t)(c0 + ch) * NHW + rg * NW + xk * 4;
                __builtin_amdgcn_global_load_lds(
                    (const __attribute__((address_space(1))) void*)src,
                    (__attribute__((address_space(3))) void*)(dst + k * 4),
                    16, 0, 0);
            }
        }
    };

    // compute geometry: tid<224 -> quad (8 rows x 14 quads) x chgroup(2)
    int chg = tid / NQ;                 // 0..1, each handles 4 ch per chunk
    int quad = tid - chg * NQ;          // 0..111
    int r = quad / 14, qx = quad - r * 14, x0 = qx * 4;
    int xl = x0 ? x0 - 1 : 0;
    int xr = (x0 + 4 < NW) ? x0 + 4 : NW - 1;

    float n0 = 0.f, n1 = 0.f, n2 = 0.f, n3 = 0.f;
    float h0 = 0.f, h1 = 0.f, h2 = 0.f, h3 = 0.f;
    float w0 = 0.f, w1 = 0.f, w2 = 0.f, w3 = 0.f;

    stage(0, buf[0]);
    __syncthreads();                            // drains staging
    for (int ci = 0; ci < NCHUNK; ++ci) {
        if (ci + 1 < NCHUNK) stage(ci + 1, buf[(ci + 1) & 1]);
        if (tid < 2 * NQ) {
            const float* sbf = buf[ci & 1];
#pragma unroll
            for (int c = 0; c < 4; ++c) {
                const float* Bm = sbf + (chg * 4 + c) * (RS * NW) + (r + 1) * NW;
                float4 v = *(const float4*)(Bm + x0);
                float  l = Bm[xl];
                float  rr = Bm[xr];
                float4 u = *(const float4*)(Bm + NW + x0);   // global y+1
                float4 d = *(const float4*)(Bm - NW + x0);   // global y-1
                n0 += v.x * v.x; n1 += v.y * v.y; n2 += v.z * v.z; n3 += v.w * v.w;
                h0 += l * v.y;   h1 += v.x * v.z; h2 += v.y * v.w; h3 += v.z * rr;
                w0 += u.x * d.x; w1 += u.y * d.y; w2 += u.z * d.z; w3 += u.w * d.w;
            }
        }
        __syncthreads();   // compute done + next stage landed
    }

    if (tid < 2 * NQ) {
        float* rb = redbuf[quad][chg];
        rb[0] = n0; rb[1] = n1; rb[2]  = n2; rb[3]  = n3;
        rb[4] = h0; rb[5] = h1; rb[6]  = h2; rb[7]  = h3;
        rb[8] = w0; rb[9] = w1; rb[10] = w2; rb[11] = w3;
    }
    __syncthreads();

    // maps layout: [chq][class n/h/v][B*HW]
    float* mbase = maps + (size_t)chq * 3 * MAPS;
    for (int oi = tid; oi < NQ * 12; oi += 256) {
        int q = oi / 12, comp = oi - q * 12;
        float acc = redbuf[q][0][comp] + redbuf[q][1][comp];
        int r2 = q / 14, qx2 = q - r2 * 14;
        int j = comp & 3;
        float* m = mbase + (size_t)(comp >> 2) * MAPS;   // 0:n 1:h 2:v
        m[((size_t)b * NH + y0 + r2) * NW + qx2 * 4 + j] = acc;
    }
}

// ---- kernel 2: sim-finish + per-slice histogram -----------------------------
// Block = (batch, 224-px slice). Same per-pixel FP math as R13's sim (bit-
// identical sv). Additionally builds a 4096-bin LDS histogram of this slice's
// svals (bits[31:20]) and writes it as a uchar slice (max count 224 < 256) —
// pre-computing topk's stage-0 histogram on a WIDE grid.
__global__ void __launch_bounds__(256)
sim_kernel(const float* __restrict__ maps, unsigned int* __restrict__ sv,
           unsigned char* __restrict__ slices) {
    __shared__ unsigned int hist[NBIN];     // 16 KB

    int bid = blockIdx.x;              // 224 = 16 b x 14 slices
    int b = bid / SPB;
    int sl = bid - b * SPB;
    int tid = threadIdx.x;

    for (int j = tid; j < NBIN; j += 256) hist[j] = 0u;
    __syncthreads();

    if (tid < SPX) {
        int i = sl * SPX + tid;        // pixel within batch
        int pix = b * NHW + i;
        int y = i / NW, x = i - y * NW;
        int xl = (x > 0) ? x - 1 : 0;
        int xr = (x < NW - 1) ? x + 1 : NW - 1;
        int yu = (y < NH - 1) ? y + 1 : NH - 1;
        int yd = (y > 0) ? y - 1 : 0;
        int il = y * NW + xl, ir = y * NW + xr;
        int iu = yu * NW + x, id = yd * NW + x;

        float nl = 0.f, nr = 0.f, nu = 0.f, nd = 0.f, h = 0.f, v = 0.f;
#pragma unroll
        for (int q = 0; q < 4; ++q) {
            const float* nq = maps + (size_t)(q * 3 + 0) * MAPS + (size_t)b * NHW;
            const float* hq = maps + (size_t)(q * 3 + 1) * MAPS + (size_t)b * NHW;
            const float* vq = maps + (size_t)(q * 3 + 2) * MAPS + (size_t)b * NHW;
            nl += nq[il]; nr += nq[ir]; nu += nq[iu]; nd += nq[id];
            h  += hq[i];  v  += vq[i];
        }
        float s = 0.5f * (h / (sqrtf(nl) * sqrtf(nr)) + v / (sqrtf(nu) * sqrtf(nd)));
        unsigned int fv = flip_f32(s);
        sv[pix] = fv;
        atomicAdd(&hist[fv >> 20], 1u);
    }
    __syncthreads();

    // write 4096 uchar counts (4 KB), coalesced
    unsigned char* out = slices + (size_t)bid * NBIN;
    for (int j = tid; j < NBIN / 4; j += 256) {
        unsigned int h4 = (hist[4 * j + 0] & 0xFFu)
                        | ((hist[4 * j + 1] & 0xFFu) << 8)
                        | ((hist[4 * j + 2] & 0xFFu) << 16)
                        | ((hist[4 * j + 3] & 0xFFu) << 24);
        ((unsigned int*)out)[j] = h4;
    }
}

// ---- kernel 3: per-batch top-K from precomputed histograms ------------------
// Stage 0 bins come straight from the 14 uchar slices into registers — no LDS
// staging, no zeroing, no atomic pass (was ~500-way serialized on
// concentrated values), ~6 barriers instead of ~15. Refinement stages (rare
// heavy-tie case) re-scan sv from global, same algorithm as R13 -> identical
// selection. Then ballot-compaction + counting-rank as R13.
__global__ void __launch_bounds__(1024)
topk_kernel(const unsigned int* __restrict__ sv,
            const unsigned char* __restrict__ slices,
            int* __restrict__ idx_out, float* __restrict__ vals_out,
            float* __restrict__ y_out, float* __restrict__ x_out) {
    __shared__ unsigned int hist[NBIN];          // refinement only
    __shared__ unsigned int wtot[16];
    __shared__ unsigned long long cand[CAP];
    __shared__ unsigned int sh_prefix, sh_mask;
    __shared__ int sh_above, sh_setS, sh_done, sh_cnt;

    const int b = blockIdx.x;
    const int tid = threadIdx.x;
    const int lane = tid & 63;
    const int wv = tid >> 6;
    const unsigned int* svb = sv + (size_t)b * NHW;

    if (tid == 0) { sh_prefix = 0u; sh_mask = 0u; sh_above = 0; sh_done = 0; }

    // ---- stage 0: bins 4t..4t+3 summed from the 14 uchar4 slices ----
    unsigned int b0 = 0, b1 = 0, b2 = 0, b3 = 0;
    {
        const unsigned int* slb = (const unsigned int*)(slices + (size_t)b * SPB * NBIN);
#pragma unroll
        for (int s = 0; s < SPB; ++s) {
            unsigned int q = slb[s * (NBIN / 4) + tid];
            b0 += q & 0xFFu;
            b1 += (q >> 8) & 0xFFu;
            b2 += (q >> 16) & 0xFFu;
            b3 += (q >> 24) & 0xFFu;
        }
    }
    __syncthreads();                   // covers sh_ init
    {
        const unsigned int kneed = NK;
        unsigned int lsum = b0 + b1 + b2 + b3;
        unsigned int s = lsum;
#pragma unroll
        for (int d = 1; d < 64; d <<= 1) {
            unsigned int t2 = __shfl_down(s, d);
            s += (lane + d < 64) ? t2 : 0u;
        }
        if (lane == 0) wtot[wv] = s;
        __syncthreads();
        unsigned int wabove = 0;
        for (int w = wv + 1; w < 16; ++w) wabove += wtot[w];
        unsigned int thr_above = wabove + (s - lsum);
        unsigned int suf3 = thr_above + b3;
        unsigned int suf2 = suf3 + b2;
        unsigned int suf1 = suf2 + b1;
        unsigned int suf0 = suf1 + b0;
        if (suf0 >= kneed && thr_above < kneed) {
            int c; unsigned int above, hc;
            if (suf3 >= kneed)      { c = 4 * tid + 3; above = thr_above; hc = b3; }
            else if (suf2 >= kneed) { c = 4 * tid + 2; above = suf3;      hc = b2; }
            else if (suf1 >= kneed) { c = 4 * tid + 1; above = suf2;      hc = b1; }
            else                    { c = 4 * tid + 0; above = suf1;      hc = b0; }
            sh_above = (int)above;
            sh_setS = (int)hc;
            sh_prefix = ((unsigned int)c) << 20;
            sh_mask = 0xFFFu << 20;
            if ((int)above + (int)hc <= CAP) sh_done = 1;
        }
    }

    // ---- refinement stages (rare; re-scan sv from global, R13 semantics) ----
    const int shifts[2] = {8, 0};
    const unsigned int wmasks[2] = {0xFFFu, 0xFFu};
    for (int st = 0; st < 2; ++st) {
        __syncthreads();
        int kneed = NK - sh_above;
        if (sh_done) break;
        for (int i = tid; i < NBIN; i += 1024) hist[i] = 0u;
        __syncthreads();
        unsigned int pfx = sh_prefix, msk = sh_mask;
        int shift = shifts[st];
        unsigned int wmask = wmasks[st];
        for (int i = tid; i < NHW; i += 1024) {
            unsigned int v = svb[i];
            if ((v & msk) == pfx) atomicAdd(&hist[(v >> shift) & wmask], 1u);
        }
        __syncthreads();
        unsigned int c0 = hist[4 * tid], c1 = hist[4 * tid + 1];
        unsigned int c2 = hist[4 * tid + 2], c3 = hist[4 * tid + 3];
        unsigned int lsum = c0 + c1 + c2 + c3;
        unsigned int s = lsum;
#pragma unroll
        for (int d = 1; d < 64; d <<= 1) {
            unsigned int t2 = __shfl_down(s, d);
            s += (lane + d < 64) ? t2 : 0u;
        }
        if (lane == 0) wtot[wv] = s;
        __syncthreads();
        unsigned int wabove = 0;
        for (int w = wv + 1; w < 16; ++w) wabove += wtot[w];
        unsigned int thr_above = wabove + (s - lsum);
        unsigned int suf3 = thr_above + c3;
        unsigned int suf2 = suf3 + c2;
        unsigned int suf1 = suf2 + c1;
        unsigned int suf0 = suf1 + c0;
        if (suf0 >= (unsigned int)kneed && thr_above < (unsigned int)kneed) {
            int c; unsigned int above, hc;
            if (suf3 >= (unsigned int)kneed)      { c = 4 * tid + 3; above = thr_above; hc = c3; }
            else if (suf2 >= (unsigned int)kneed) { c = 4 * tid + 2; above = suf3;      hc = c2; }
            else if (suf1 >= (unsigned int)kneed) { c = 4 * tid + 1; above = suf2;      hc = c1; }
            else                                  { c = 4 * tid + 0; above = suf1;      hc = c0; }
            sh_above += (int)above;
            sh_setS = (int)hc;
            sh_prefix = pfx | ((unsigned int)c << shift);
            sh_mask = msk | (wmask << shift);
            if (sh_above + sh_setS <= CAP || st == 1) sh_done = 1;
        }
    }
    __syncthreads();

    // ---- ballot-aggregated compaction of candidates v >= T (from global) ----
    if (tid == 0) sh_cnt = 0;
    __syncthreads();
    unsigned int T = sh_prefix;
    for (int i = tid; i < NHW; i += 1024) {
        unsigned int v = svb[i];
        bool keep = (v >= T);
        unsigned long long m = __ballot(keep);
        int basep = 0;
        if (lane == 0) basep = atomicAdd(&sh_cnt, __popcll(m));
        basep = __shfl(basep, 0);
        if (keep) {
            int pos = basep + __popcll(m & ((1ull << lane) - 1ull));
            if (pos < CAP)
                cand[pos] = ((unsigned long long)v << 32) |
                            (unsigned long long)(0xFFFFFFFFu - (unsigned int)i);
        }
    }
    __syncthreads();
    int nc = sh_cnt; if (nc > CAP) nc = CAP;

    // counting-rank: thread t ranks its candidate against all nc
    if (tid < nc) {
        unsigned long long my = cand[tid];
        int rank = 0;
        for (int i = 0; i < nc; ++i) rank += (cand[i] > my);
        if (rank < NK) {
            unsigned int lo = (unsigned int)(my & 0xFFFFFFFFull);
            int idx = (int)(0xFFFFFFFFu - lo);
            float val = unflip_f32((unsigned int)(my >> 32));
            int o = b * NK + rank;
            idx_out[o] = idx;
            vals_out[o] = val;
            y_out[o] = (float)(idx / NW);
            x_out[o] = (float)(idx % NW);
        }
    }
}

// ---- kernel 4: gather point features [B,K,C] (R13-exact scattered) ----------
#define GCT 8
__global__ void __launch_bounds__(256)
gather_kernel(const float* __restrict__ f, const int* __restrict__ idx,
              float* __restrict__ out) {
    int bid = blockIdx.x;              // 512 = 16 b x 32 ctiles
    int b = bid >> 5;
    int c0 = (bid & 31) * GCT;
    int t = threadIdx.x;               // point rank k
    int p = idx[b * NK + t];
    const float* fb = f + (size_t)b * NC * NHW + (size_t)c0 * NHW;

    float v[GCT];
#pragma unroll
    for (int ci = 0; ci < GCT; ++ci) v[ci] = fb[(size_t)ci * NHW + p];

    float4 a = make_float4(v[0], v[1], v[2], v[3]);
    float4 b4 = make_float4(v[4], v[5], v[6], v[7]);
    float* op = out + ((size_t)b * NK + t) * NC + c0;
    *(float4*)op = a;
    *(float4*)(op + 4) = b4;
}

extern "C" void kernel_launch(void* const* d_in, const int* in_sizes, int n_in,
                              void* d_out, int out_size, void* d_ws, size_t ws_size,
                              hipStream_t stream) {
    const float* f = (const float*)d_in[0];

    // output layout: point_feat [B,K,C] | vals [B,K] | ycoord [B,K] | xcoord [B,K]
    float* out_feat = (float*)d_out;
    float* out_vals = out_feat + (size_t)NB * NK * NC;
    float* out_y    = out_vals + (size_t)NB * NK;
    float* out_x    = out_y    + (size_t)NB * NK;

    // workspace: 12 partial maps | sv map | hist slices | idx
    float* maps = (float*)d_ws;
    unsigned int* sv = (unsigned int*)(maps + 12 * (size_t)MAPS);
    unsigned char* slices = (unsigned char*)(sv + MAPS);
    int* idx = (int*)(slices + (size_t)NB * SPB * NBIN);

    pass1_kernel<<<P1_BLOCKS, 256, 0, stream>>>(f, maps);
    sim_kernel<<<NB * SPB, 256, 0, stream>>>(maps, sv, slices);
    topk_kernel<<<NB, 1024, 0, stream>>>(sv, slices, idx, out_vals, out_y, out_x);
    gather_kernel<<<NB * (NC / GCT), 256, 0, stream>>>(f, idx, out_feat);
}

// Round 19
// 36.680 us; speedup vs baseline: 1.2332x; 1.0482x over previous
//
#include <hip/hip_runtime.h>

#define NB 16
#define NC 256
#define NH 56
#define NW 56
#define NHW (NH * NW)          // 3136
#define NK 256
#define CAP 1024

// pass1 geometry (R13-exact): 8-row band x quarter channels -> 448 blocks
#define BR 8                   // compute rows per band
#define RS 10                  // staged rows (8 compute + 2 halo)
#define CS 8                   // channels per staged chunk
#define CQ 64                  // channels per block (quarter)
#define NCHUNK (CQ / CS)       // 8 chunks per block
#define CHUNK16 (CS * RS * NW / 4)        // 1120 16B-chunks per stage
#define NBAND (NH / BR)                   // 7
#define P1_BLOCKS (NB * NBAND * 4)        // 448 (56 per XCD)
#define NQ (BR * (NW / 4))                // 112 quads per band
#define MAPS (NB * NHW)                   // elements per map

// ---- sortable-float helpers -------------------------------------------------
__device__ inline unsigned int flip_f32(float f) {
    unsigned int u = __float_as_uint(f);
    return (u & 0x80000000u) ? ~u : (u | 0x80000000u);
}
__device__ inline float unflip_f32(unsigned int u) {
    u = (u & 0x80000000u) ? (u ^ 0x80000000u) : ~u;
    return __uint_as_float(u);
}

// ---- kernel 1: partial norm2 / hprod / vprod maps (R13-exact) ---------------
__global__ void __launch_bounds__(256)
pass1_kernel(const float* __restrict__ f, float* __restrict__ maps) {
    __shared__ __align__(16) float buf[2][CS * RS * NW];   // 2 x 17920 B
    __shared__ float redbuf[NQ][2][12];                    // 10752 B

    int bid = blockIdx.x;
    int sb = (bid & 7) * (P1_BLOCKS / 8) + (bid >> 3);   // XCD-chunked
    int b = sb / 28;
    int rem0 = sb - b * 28;
    int band = rem0 >> 2;          // 0..6
    int chq = rem0 & 3;            // channel quarter
    int y0 = band * BR;
    int tid = threadIdx.x;
    const float* fb = f + (size_t)b * NC * NHW + (size_t)chq * CQ * NHW;

    auto stage = [&](int ci, float* dst) {
        int c0 = ci * CS;
#pragma unroll
        for (int i = 0; i < 5; ++i) {
            int k = tid + 256 * i;
            if (k < CHUNK16) {
                int ch = k / (RS * 14);            // 140 16B-chunks per channel
                int rem = k - ch * (RS * 14);
                int rl = rem / 14;                 // staged row 0..9
                int xk = rem - rl * 14;            // 16B chunk within row
                int rg = y0 - 1 + rl;
                rg = rg < 0 ? 0 : (rg > NH - 1 ? NH - 1 : rg);
                const float* src = fb + (size_t)(c0 + ch) * NHW + rg * NW + xk * 4;
                __builtin_amdgcn_global_load_lds(
                    (const __attribute__((address_space(1))) void*)src,
                    (__attribute__((address_space(3))) void*)(dst + k * 4),
                    16, 0, 0);
            }
        }
    };

    // compute geometry: tid<224 -> quad (8 rows x 14 quads) x chgroup(2)
    int chg = tid / NQ;                 // 0..1, each handles 4 ch per chunk
    int quad = tid - chg * NQ;          // 0..111
    int r = quad / 14, qx = quad - r * 14, x0 = qx * 4;
    int xl = x0 ? x0 - 1 : 0;
    int xr = (x0 + 4 < NW) ? x0 + 4 : NW - 1;

    float n0 = 0.f, n1 = 0.f, n2 = 0.f, n3 = 0.f;
    float h0 = 0.f, h1 = 0.f, h2 = 0.f, h3 = 0.f;
    float w0 = 0.f, w1 = 0.f, w2 = 0.f, w3 = 0.f;

    stage(0, buf[0]);
    __syncthreads();                            // drains staging
    for (int ci = 0; ci < NCHUNK; ++ci) {
        if (ci + 1 < NCHUNK) stage(ci + 1, buf[(ci + 1) & 1]);
        if (tid < 2 * NQ) {
            const float* sbf = buf[ci & 1];
#pragma unroll
            for (int c = 0; c < 4; ++c) {
                const float* Bm = sbf + (chg * 4 + c) * (RS * NW) + (r + 1) * NW;
                float4 v = *(const float4*)(Bm + x0);
                float  l = Bm[xl];
                float  rr = Bm[xr];
                float4 u = *(const float4*)(Bm + NW + x0);   // global y+1
                float4 d = *(const float4*)(Bm - NW + x0);   // global y-1
                n0 += v.x * v.x; n1 += v.y * v.y; n2 += v.z * v.z; n3 += v.w * v.w;
                h0 += l * v.y;   h1 += v.x * v.z; h2 += v.y * v.w; h3 += v.z * rr;
                w0 += u.x * d.x; w1 += u.y * d.y; w2 += u.z * d.z; w3 += u.w * d.w;
            }
        }
        __syncthreads();   // compute done + next stage landed
    }

    if (tid < 2 * NQ) {
        float* rb = redbuf[quad][chg];
        rb[0] = n0; rb[1] = n1; rb[2]  = n2; rb[3]  = n3;
        rb[4] = h0; rb[5] = h1; rb[6]  = h2; rb[7]  = h3;
        rb[8] = w0; rb[9] = w1; rb[10] = w2; rb[11] = w3;
    }
    __syncthreads();

    // maps layout: [chq][class n/h/v][B*HW]
    float* mbase = maps + (size_t)chq * 3 * MAPS;
    for (int oi = tid; oi < NQ * 12; oi += 256) {
        int q = oi / 12, comp = oi - q * 12;
        float acc = redbuf[q][0][comp] + redbuf[q][1][comp];
        int r2 = q / 14, qx2 = q - r2 * 14;
        int j = comp & 3;
        float* m = mbase + (size_t)(comp >> 2) * MAPS;   // 0:n 1:h 2:v
        m[((size_t)b * NH + y0 + r2) * NW + qx2 * 4 + j] = acc;
    }
}

// ---- kernel 2: sim-finish (R13-exact, wide) ---------------------------------
__global__ void __launch_bounds__(256)
sim_kernel(const float* __restrict__ maps, unsigned int* __restrict__ sv) {
    int pix = blockIdx.x * 256 + threadIdx.x;
    if (pix >= NB * NHW) return;
    int b = pix / NHW, i = pix - b * NHW;

    int y = i / NW, x = i - y * NW;
    int xl = (x > 0) ? x - 1 : 0;
    int xr = (x < NW - 1) ? x + 1 : NW - 1;
    int yu = (y < NH - 1) ? y + 1 : NH - 1;
    int yd = (y > 0) ? y - 1 : 0;
    int il = y * NW + xl, ir = y * NW + xr;
    int iu = yu * NW + x, id = yd * NW + x;

    float nl = 0.f, nr = 0.f, nu = 0.f, nd = 0.f, h = 0.f, v = 0.f;
#pragma unroll
    for (int q = 0; q < 4; ++q) {
        const float* nq = maps + (size_t)(q * 3 + 0) * MAPS + (size_t)b * NHW;
        const float* hq = maps + (size_t)(q * 3 + 1) * MAPS + (size_t)b * NHW;
        const float* vq = maps + (size_t)(q * 3 + 2) * MAPS + (size_t)b * NHW;
        nl += nq[il]; nr += nq[ir]; nu += nq[iu]; nd += nq[id];
        h  += hq[i];  v  += vq[i];
    }
    float s = 0.5f * (h / (sqrtf(nl) * sqrtf(nr)) + v / (sqrtf(nu) * sqrtf(nd)));
    sv[pix] = flip_f32(s);
}

// ---- kernel 3: per-batch top-K (R13 algorithm, svals in REGISTERS) ----------
// Each of the 1024 threads holds its <=4 strided svals in registers (rv0..rv3,
// statically indexed): the hist pass and ballot-compaction read registers
// instead of an LDS staging array. Identical iteration order -> identical
// candidate order -> bit-identical output. Saves 12.5 KB LDS + 2 LDS passes.
__global__ void __launch_bounds__(1024)
topk_kernel(const unsigned int* __restrict__ sv, int* __restrict__ idx_out,
            float* __restrict__ vals_out, float* __restrict__ y_out,
            float* __restrict__ x_out) {
    __shared__ unsigned int hist[4096];
    __shared__ unsigned int wtot[16];
    __shared__ unsigned long long cand[CAP];
    __shared__ unsigned int sh_prefix, sh_mask;
    __shared__ int sh_above, sh_setS, sh_done, sh_cnt;

    const int b = blockIdx.x;
    const int tid = threadIdx.x;
    const int lane = tid & 63;
    const int wv = tid >> 6;
    const unsigned int* svb = sv + (size_t)b * NHW;

    // register-resident svals: i = tid + 1024*j, j<3 always, j=3 iff tid<64
    const bool has3 = (tid < 64);       // 3136 = 3*1024 + 64
    unsigned int rv0 = svb[tid];
    unsigned int rv1 = svb[tid + 1024];
    unsigned int rv2 = svb[tid + 2048];
    unsigned int rv3 = has3 ? svb[tid + 3072] : 0u;

    if (tid == 0) { sh_prefix = 0u; sh_mask = 0u; sh_above = 0; sh_done = 0; }

    const int shifts[3] = {20, 8, 0};
    const unsigned int wmasks[3] = {0xFFFu, 0xFFFu, 0xFFu};
    for (int st = 0; st < 3; ++st) {
        __syncthreads();
        int kneed = NK - sh_above;          // read post-barrier, pre-update
        if (sh_done) break;
        for (int i = tid; i < 4096; i += 1024) hist[i] = 0u;
        __syncthreads();
        unsigned int pfx = sh_prefix, msk = sh_mask;
        int shift = shifts[st];
        unsigned int wmask = wmasks[st];
        if ((rv0 & msk) == pfx) atomicAdd(&hist[(rv0 >> shift) & wmask], 1u);
        if ((rv1 & msk) == pfx) atomicAdd(&hist[(rv1 >> shift) & wmask], 1u);
        if ((rv2 & msk) == pfx) atomicAdd(&hist[(rv2 >> shift) & wmask], 1u);
        if (has3 && (rv3 & msk) == pfx) atomicAdd(&hist[(rv3 >> shift) & wmask], 1u);
        __syncthreads();
        unsigned int b0 = hist[4 * tid], b1 = hist[4 * tid + 1];
        unsigned int b2 = hist[4 * tid + 2], b3 = hist[4 * tid + 3];
        unsigned int lsum = b0 + b1 + b2 + b3;
        unsigned int s = lsum;
#pragma unroll
        for (int d = 1; d < 64; d <<= 1) {
            unsigned int t2 = __shfl_down(s, d);
            s += (lane + d < 64) ? t2 : 0u;
        }
        if (lane == 0) wtot[wv] = s;        // wave total
        __syncthreads();
        unsigned int wabove = 0;
        for (int w = wv + 1; w < 16; ++w) wabove += wtot[w];
        unsigned int thr_above = wabove + (s - lsum);   // strictly above my bins
        unsigned int suf3 = thr_above + b3;
        unsigned int suf2 = suf3 + b2;
        unsigned int suf1 = suf2 + b1;
        unsigned int suf0 = suf1 + b0;
        if (suf0 >= (unsigned int)kneed && thr_above < (unsigned int)kneed) {
            int c; unsigned int above, hc;
            if (suf3 >= (unsigned int)kneed)      { c = 4 * tid + 3; above = thr_above; hc = b3; }
            else if (suf2 >= (unsigned int)kneed) { c = 4 * tid + 2; above = suf3;      hc = b2; }
            else if (suf1 >= (unsigned int)kneed) { c = 4 * tid + 1; above = suf2;      hc = b1; }
            else                                  { c = 4 * tid + 0; above = suf1;      hc = b0; }
            sh_above += (int)above;
            sh_setS = (int)hc;
            sh_prefix = pfx | ((unsigned int)c << shift);
            sh_mask = msk | (wmask << shift);
            if (sh_above + sh_setS <= CAP || st == 2) sh_done = 1;
        }
    }
    __syncthreads();

    // ballot-aggregated compaction of candidates v >= T (from registers)
    if (tid == 0) sh_cnt = 0;
    __syncthreads();
    unsigned int T = sh_prefix;
#pragma unroll
    for (int j = 0; j < 4; ++j) {
        bool active = (j < 3) || has3;
        unsigned int v = (j == 0) ? rv0 : (j == 1) ? rv1 : (j == 2) ? rv2 : rv3;
        bool keep = active && (v >= T);
        unsigned long long m = __ballot(keep);
        int basep = 0;
        if (lane == 0) basep = atomicAdd(&sh_cnt, __popcll(m));
        basep = __shfl(basep, 0);
        if (keep) {
            int pos = basep + __popcll(m & ((1ull << lane) - 1ull));
            int i = tid + 1024 * j;
            if (pos < CAP)
                cand[pos] = ((unsigned long long)v << 32) |
                            (unsigned long long)(0xFFFFFFFFu - (unsigned int)i);
        }
    }
    __syncthreads();
    int nc = sh_cnt; if (nc > CAP) nc = CAP;

    // counting-rank: thread t ranks its candidate against all nc
    if (tid < nc) {
        unsigned long long my = cand[tid];
        int rank = 0;
        for (int i = 0; i < nc; ++i) rank += (cand[i] > my);
        if (rank < NK) {
            unsigned int lo = (unsigned int)(my & 0xFFFFFFFFull);
            int idx = (int)(0xFFFFFFFFu - lo);
            float val = unflip_f32((unsigned int)(my >> 32));
            int o = b * NK + rank;
            idx_out[o] = idx;
            vals_out[o] = val;
            y_out[o] = (float)(idx / NW);
            x_out[o] = (float)(idx % NW);
        }
    }
}

// ---- kernel 4: gather point features [B,K,C] (R13-exact scattered) ----------
#define GCT 8
__global__ void __launch_bounds__(256)
gather_kernel(const float* __restrict__ f, const int* __restrict__ idx,
              float* __restrict__ out) {
    int bid = blockIdx.x;              // 512 = 16 b x 32 ctiles
    int b = bid >> 5;
    int c0 = (bid & 31) * GCT;
    int t = threadIdx.x;               // point rank k
    int p = idx[b * NK + t];
    const float* fb = f + (size_t)b * NC * NHW + (size_t)c0 * NHW;

    float v[GCT];
#pragma unroll
    for (int ci = 0; ci < GCT; ++ci) v[ci] = fb[(size_t)ci * NHW + p];

    float4 a = make_float4(v[0], v[1], v[2], v[3]);
    float4 b4 = make_float4(v[4], v[5], v[6], v[7]);
    float* op = out + ((size_t)b * NK + t) * NC + c0;
    *(float4*)op = a;
    *(float4*)(op + 4) = b4;
}

extern "C" void kernel_launch(void* const* d_in, const int* in_sizes, int n_in,
                              void* d_out, int out_size, void* d_ws, size_t ws_size,
                              hipStream_t stream) {
    const float* f = (const float*)d_in[0];

    // output layout: point_feat [B,K,C] | vals [B,K] | ycoord [B,K] | xcoord [B,K]
    float* out_feat = (float*)d_out;
    float* out_vals = out_feat + (size_t)NB * NK * NC;
    float* out_y    = out_vals + (size_t)NB * NK;
    float* out_x    = out_y    + (size_t)NB * NK;

    // workspace: 12 partial maps (n,h,v x 4 quarters) | svals map | idx
    float* maps = (float*)d_ws;
    unsigned int* sv = (unsigned int*)(maps + 12 * (size_t)MAPS);
    int* idx = (int*)(sv + MAPS);

    pass1_kernel<<<P1_BLOCKS, 256, 0, stream>>>(f, maps);
    sim_kernel<<<(NB * NHW + 255) / 256, 256, 0, stream>>>(maps, sv);
    topk_kernel<<<NB, 1024, 0, stream>>>(sv, idx, out_vals, out_y, out_x);
    gather_kernel<<<NB * (NC / GCT), 256, 0, stream>>>(f, idx, out_feat);
}